// Round 3
// baseline (198.820 us; speedup 1.0000x reference)
//
#include <hip/hip_runtime.h>

typedef float  float4_t __attribute__((ext_vector_type(4)));
typedef unsigned int uint4_t __attribute__((ext_vector_type(4)));
typedef short  bf16x8  __attribute__((ext_vector_type(8)));
typedef float  f32x4   __attribute__((ext_vector_type(4)));

#define A_N    256
#define NVIEW  8
#define FEAT   256
#define BANK   2048
#define NROWS  2048       // A_N * NVIEW
#define BM     256
#define BN     256
#define BK     32
#define NKT    8          // FEAT / BK
#define INV_TEMP 10.0f
#define A_CHUNKS 65536        // 2048*256/8 bf16 chunks of 8
#define B_CHUNKS 1179648      // 36864*256/8
#define TOT_CHUNKS (A_CHUNKS + B_CHUNKS)

typedef unsigned int __attribute__((address_space(1))) guint;
typedef unsigned int __attribute__((address_space(3))) luint;

// round-to-nearest-even f32 -> bf16, two at a time packed into a uint
__device__ inline unsigned int pack_bf16x2(float lo, float hi) {
    unsigned int ulo = __builtin_bit_cast(unsigned int, lo);
    unsigned int uhi = __builtin_bit_cast(unsigned int, hi);
    unsigned int rl = 0x7FFFu + ((ulo >> 16) & 1u);
    unsigned int rh = 0x7FFFu + ((uhi >> 16) & 1u);
    return ((ulo + rl) >> 16) | ((uhi + rh) & 0xFFFF0000u);
}

__global__ __launch_bounds__(256) void zero_kernel(float* __restrict__ S, float* __restrict__ out) {
    int i = blockIdx.x * 256 + threadIdx.x;
    if (i < NROWS) S[i] = 0.0f;
    if (i == 0) out[0] = 0.0f;
}

// Pass 0: convert fp32 -> bf16 ONCE, pre-packed in MFMA fragment order for
// 256x32 tiles so pass1 DMAs linearly into LDS with global_load_lds.
// Tile = 256 rows x 32 k = 1024 chunks of 8 bf16.
// chunk ch: frag = ch>>6 (= row-frag rf, 16 rows), ln = ch&63;
//   row = rf*16 + (ln&15), k = (ln>>4)*8.
__global__ __launch_bounds__(256) void pass0_pack(
    const float* __restrict__ X,    // X_anchor [256][8][256]
    const float* __restrict__ Q,    // queue [19][2048][256]
    unsigned short* __restrict__ Abuf,
    unsigned short* __restrict__ Bbuf)
{
    const int cid = blockIdx.x * 256 + threadIdx.x;
    if (cid >= TOT_CHUNKS) return;
    const int ch = cid & 1023;
    const int rf = ch >> 6, ln = ch & 63;
    const int rloc = (rf << 4) | (ln & 15);
    const int kloc = (ln >> 4) << 3;
    const float* src;
    unsigned short* dst;
    if (cid < A_CHUNKS) {
        const int tileid = cid >> 10;               // rt*8 + kt
        const int rt = tileid >> 3, kt = tileid & 7;
        const int r = rt * BM + rloc;               // anchor_feature row: v*256+a
        const int k = kt * BK + kloc;
        src = X + (((size_t)((r & 255) * NVIEW + (r >> 8))) << 8) + k;
        dst = Abuf + ((size_t)cid << 3);
    } else {
        const int bcid = cid - A_CHUNKS;
        const int tileid = bcid >> 10;              // ct*8 + kt
        const int ct = tileid >> 3, kt = tileid & 7;
        const int j = ct * BN + rloc;               // contrast col (class 0 skipped)
        const int k = kt * BK + kloc;
        src = Q + (((size_t)(BANK + j)) << 8) + k;
        dst = Bbuf + ((size_t)bcid << 3);
    }
    float4_t v0 = *(const float4_t*)src;
    float4_t v1 = *(const float4_t*)(src + 4);
    uint4_t p = { pack_bf16x2(v0.x, v0.y), pack_bf16x2(v0.z, v0.w),
                  pack_bf16x2(v1.x, v1.y), pack_bf16x2(v1.z, v1.w) };
    *(uint4_t*)dst = p;
}

// Pass 1: 256x256-tile bf16 MFMA GEMM, 8 waves (2x4), BK=32, double-buffered
// LDS (64 KB), 2-phase schedule: STAGE(next) issued before compute(cur), one
// barrier per K-step so the load drain hides under ~1240 cyc of MFMA.
//   - accumulates S[r] += sum_j exp(logit[r][j])
//   - stores logit into pos[r][col&2047] when col's class == y[r&255]
__global__ __launch_bounds__(512, 1) void pass1_gemm(
    const unsigned short* __restrict__ Abuf,
    const unsigned short* __restrict__ Bbuf,
    const int*   __restrict__ y,
    float* __restrict__ S,
    float* __restrict__ pos)
{
    __shared__ __align__(16) unsigned short lA[2][8192];   // 2 x 16 KB
    __shared__ __align__(16) unsigned short lB[2][8192];

    // bijective XCD swizzle: 1152 blocks, 1152 % 8 == 0
    const int bid = blockIdx.x;
    const int wg  = (bid & 7) * 144 + (bid >> 3);
    const int rt  = wg & 7;          // 8 row tiles (fast -> A L2-resident per XCD)
    const int ct  = wg >> 3;         // 144 col tiles

    const int t    = threadIdx.x;
    const int lane = t & 63;
    const int w    = t >> 6;
    const int wr   = w >> 2, wc = w & 3;    // 2x4 waves, wave tile 128x64

    const unsigned short* Ab0 = Abuf + ((size_t)(rt * NKT) << 13);  // 8192 shorts/tile
    const unsigned short* Bb0 = Bbuf + ((size_t)(ct * NKT) << 13);

    f32x4 acc[8][4] = {};

    auto STAGE = [&](int buf, int kt) {
        const unsigned short* Ab = Ab0 + ((size_t)kt << 13);
        const unsigned short* Bb = Bb0 + ((size_t)kt << 13);
        #pragma unroll
        for (int i = 0; i < 2; ++i) {
            const int cb = (w * 2 + i) << 6;     // wave-uniform chunk base
            __builtin_amdgcn_global_load_lds((const guint*)(Ab + ((size_t)(cb + lane) << 3)),
                                             (luint*)&lA[buf][(size_t)cb << 3], 16, 0, 0);
            __builtin_amdgcn_global_load_lds((const guint*)(Bb + ((size_t)(cb + lane) << 3)),
                                             (luint*)&lB[buf][(size_t)cb << 3], 16, 0, 0);
        }
    };

    STAGE(0, 0);
    __syncthreads();

    int cur = 0;
    for (int kt = 0; kt < NKT; ++kt) {
        if (kt + 1 < NKT) STAGE(cur ^ 1, kt + 1);   // issue next-tile DMA first
        bf16x8 af[8], bfv[4];
        #pragma unroll
        for (int ni = 0; ni < 4; ++ni)
            bfv[ni] = *(const bf16x8*)&lB[cur][((wc * 4 + ni) << 9) + lane * 8];
        #pragma unroll
        for (int mi = 0; mi < 8; ++mi)
            af[mi] = *(const bf16x8*)&lA[cur][((wr * 8 + mi) << 9) + lane * 8];
        #pragma unroll
        for (int mi = 0; mi < 8; ++mi)
            #pragma unroll
            for (int ni = 0; ni < 4; ++ni)
                acc[mi][ni] = __builtin_amdgcn_mfma_f32_16x16x32_bf16(af[mi], bfv[ni], acc[mi][ni], 0, 0, 0);
        __syncthreads();                             // drains vmcnt: next buf ready
        cur ^= 1;
    }

    // ---- epilogue: logits = acc*10; exp; row-sum -> atomic S; store positives ----
    const int cj = (ct >> 3) + 1;                    // class of this col tile (1..18)
    const int colbase = ct * BN + wc * 64 + (lane & 15);
    #pragma unroll
    for (int mi = 0; mi < 8; ++mi) {
        #pragma unroll
        for (int rj = 0; rj < 4; ++rj) {
            const int r = rt * BM + wr * 128 + mi * 16 + ((lane >> 4) << 2) + rj;
            const bool isPos = (y[r & 255] == cj);
            float rs = 0.0f;
            #pragma unroll
            for (int ni = 0; ni < 4; ++ni) {
                const float lv = acc[mi][ni][rj] * INV_TEMP;
                rs += __expf(lv);
                if (isPos) pos[(size_t)r * BANK + ((colbase + ni * 16) & (BANK - 1))] = lv;
            }
            rs += __shfl_xor(rs, 1);
            rs += __shfl_xor(rs, 2);
            rs += __shfl_xor(rs, 4);
            rs += __shfl_xor(rs, 8);
            if ((lane & 15) == 0) atomicAdd(&S[r], rs);
        }
    }
}

// Pass 3: per-row finish. N = S[r] - posExpSum + 2048 (zero block).
// P = sum over positives of (l - log(exp(l)+N)), excluding diagonal for class-1 rows.
__global__ __launch_bounds__(256) void pass3_kernel(
    const int* __restrict__ y, const float* __restrict__ S,
    const float* __restrict__ pos, float* __restrict__ out)
{
    __shared__ float sh[8];
    const int r = blockIdx.x;
    const int t = threadIdx.x;
    const int c = y[r & 255];
    const float4_t* row4 = (const float4_t*)(pos + (size_t)r * BANK);
    float4_t va = row4[t];
    float4_t vb = row4[t + 256];
    float l[8] = { va.x, va.y, va.z, va.w, vb.x, vb.y, vb.z, vb.w };
    float e[8];
    float eSum = 0.0f;
    #pragma unroll
    for (int i = 0; i < 8; ++i) { e[i] = __expf(l[i]); eSum += e[i]; }
    #pragma unroll
    for (int m = 1; m < 64; m <<= 1) eSum += __shfl_xor(eSum, m);
    const int w = t >> 6;
    if ((t & 63) == 0) sh[w] = eSum;
    __syncthreads();
    const float eTot = sh[0] + sh[1] + sh[2] + sh[3];
    const float N = S[r] - eTot + (float)BANK;

    float P = 0.0f;
    #pragma unroll
    for (int i = 0; i < 8; ++i) {
        const int m = (i < 4) ? (4 * t + i) : (1024 + 4 * t + (i - 4));
        const bool skip = (c == 1) && (m == r);
        if (!skip) P += l[i] - __logf(e[i] + N);
    }
    #pragma unroll
    for (int m = 1; m < 64; m <<= 1) P += __shfl_xor(P, m);
    if ((t & 63) == 0) sh[4 + w] = P;
    __syncthreads();
    if (t == 0) {
        const float Ptot = sh[4] + sh[5] + sh[6] + sh[7];
        const float denom = (c == 1) ? (float)(BANK - 1) : (float)BANK;
        atomicAdd(out, (-Ptot / denom) * (1.0f / (float)NROWS));
    }
}

extern "C" void kernel_launch(void* const* d_in, const int* in_sizes, int n_in,
                              void* d_out, int out_size, void* d_ws, size_t ws_size,
                              hipStream_t stream) {
    const float* X = (const float*)d_in[0];
    const int*   y = (const int*)d_in[1];
    const float* Q = (const float*)d_in[2];
    float* out = (float*)d_out;
    float* S   = (float*)d_ws;                                   // 2048 f32
    float* pos = S + NROWS;                                      // 2048*2048 f32 (16.8 MB)
    unsigned short* Abuf = (unsigned short*)(pos + (size_t)NROWS * BANK);   // 1 MB
    unsigned short* Bbuf = Abuf + ((size_t)A_CHUNKS << 3);                  // 18.9 MB

    zero_kernel<<<dim3(8), dim3(256), 0, stream>>>(S, out);
    pass0_pack<<<dim3(TOT_CHUNKS / 256), dim3(256), 0, stream>>>(X, Q, Abuf, Bbuf);
    pass1_gemm<<<dim3(16 * 8 * 9), dim3(512), 0, stream>>>(Abuf, Bbuf, y, S, pos);
    pass3_kernel<<<dim3(NROWS), dim3(256), 0, stream>>>(y, S, pos, out);
}

// Round 4
// 121.729 us; speedup vs baseline: 1.6333x; 1.6333x over previous
//
#include <hip/hip_runtime.h>

typedef float  float4_t __attribute__((ext_vector_type(4)));
typedef unsigned int uint4_t __attribute__((ext_vector_type(4)));
typedef short  bf16x8  __attribute__((ext_vector_type(8)));
typedef float  f32x4   __attribute__((ext_vector_type(4)));

#define A_N    256
#define NVIEW  8
#define FEAT   256
#define BANK   2048
#define NROWS  2048       // A_N * NVIEW
#define BM     128
#define BN     128
#define BK     64
#define NCT    288        // column tiles
#define INV_TEMP 10.0f
#define A_CHUNKS 65536        // 2048*256/8 bf16 chunks of 8
#define B_CHUNKS 1179648      // 36864*256/8
#define TOT_CHUNKS (A_CHUNKS + B_CHUNKS)

typedef unsigned int __attribute__((address_space(1))) guint;
typedef unsigned int __attribute__((address_space(3))) luint;

// round-to-nearest-even f32 -> bf16, two at a time packed into a uint
__device__ inline unsigned int pack_bf16x2(float lo, float hi) {
    unsigned int ulo = __builtin_bit_cast(unsigned int, lo);
    unsigned int uhi = __builtin_bit_cast(unsigned int, hi);
    unsigned int rl = 0x7FFFu + ((ulo >> 16) & 1u);
    unsigned int rh = 0x7FFFu + ((uhi >> 16) & 1u);
    return ((ulo + rl) >> 16) | ((uhi + rh) & 0xFFFF0000u);
}

__global__ __launch_bounds__(256) void zero_kernel(float* __restrict__ out) {
    if (threadIdx.x == 0 && blockIdx.x == 0) out[0] = 0.0f;
}

// Pass 0: convert fp32 -> bf16 ONCE, pre-packed in MFMA fragment order so that
// pass1 can DMA it linearly into LDS with global_load_lds (16B/lane).
// Tile = 128 rows x 64 k, 8192 bf16 = 1024 chunks of 8.
__global__ __launch_bounds__(256) void pass0_pack(
    const float* __restrict__ X,    // X_anchor [256][8][256]
    const float* __restrict__ Q,    // queue [19][2048][256]
    unsigned short* __restrict__ Abuf,
    unsigned short* __restrict__ Bbuf)
{
    const int cid = blockIdx.x * 256 + threadIdx.x;
    if (cid >= TOT_CHUNKS) return;
    const int ch = cid & 1023;
    const int frag = ch >> 6, ln = ch & 63;
    const int rf = frag >> 1, kf = frag & 1;
    const int rloc = (rf << 4) | (ln & 15);
    const int kloc = (kf << 5) | ((ln >> 4) << 3);
    const float* src;
    unsigned short* dst;
    if (cid < A_CHUNKS) {
        const int tileid = cid >> 10;               // rt*4 + kt
        const int rt = tileid >> 2, kt = tileid & 3;
        const int r = rt * BM + rloc;               // anchor_feature row: v*256+a
        const int k = kt * BK + kloc;
        src = X + (((size_t)((r & 255) * NVIEW + (r >> 8))) << 8) + k;
        dst = Abuf + ((size_t)cid << 3);
    } else {
        const int bcid = cid - A_CHUNKS;
        const int tileid = bcid >> 10;              // ct*4 + kt
        const int ct = tileid >> 2, kt = tileid & 3;
        const int j = ct * BN + rloc;               // contrast col (class 0 skipped)
        const int k = kt * BK + kloc;
        src = Q + (((size_t)(BANK + j)) << 8) + k;
        dst = Bbuf + ((size_t)bcid << 3);
    }
    float4_t v0 = *(const float4_t*)src;
    float4_t v1 = *(const float4_t*)(src + 4);
    uint4_t p = { pack_bf16x2(v0.x, v0.y), pack_bf16x2(v0.z, v0.w),
                  pack_bf16x2(v1.x, v1.y), pack_bf16x2(v1.z, v1.w) };
    *(uint4_t*)dst = p;
}

// Pass 1: logits GEMM over all 18 real classes (bf16 MFMA, pre-packed inputs).
//   - per-block row exp-sums -> LDS reduce -> part[ct][r]   (NO global atomics)
//   - stores logit into pos[r][col&2047] when col's class == y[r&255]
__global__ __launch_bounds__(256) void pass1_gemm(
    const unsigned short* __restrict__ Abuf,
    const unsigned short* __restrict__ Bbuf,
    const int*   __restrict__ y,
    float* __restrict__ part,   // [NCT][NROWS]
    float* __restrict__ pos)    // [NROWS][BANK]
{
    __shared__ __align__(16) unsigned short lA[BM * BK];
    __shared__ __align__(16) unsigned short lB[BN * BK];

    const int rt = blockIdx.x;              // 16 row tiles
    const int ct = blockIdx.y;              // 288 col tiles
    const int t    = threadIdx.x;
    const int lane = t & 63;
    const int w    = t >> 6;
    const int wr   = w >> 1, wc = w & 1;    // 2x2 waves, each 64x64

    f32x4 acc[4][4] = {};

    for (int kt = 0; kt < 4; ++kt) {
        const unsigned short* Ab = Abuf + (((size_t)(rt * 4 + kt)) << 13);
        const unsigned short* Bb = Bbuf + (((size_t)(ct * 4 + kt)) << 13);
        #pragma unroll
        for (int i = 0; i < 4; ++i) {
            const int cb = (w * 4 + i) << 6;     // wave-uniform chunk base
            __builtin_amdgcn_global_load_lds((const guint*)(Ab + ((size_t)(cb + lane) << 3)),
                                             (luint*)&lA[(size_t)cb << 3], 16, 0, 0);
            __builtin_amdgcn_global_load_lds((const guint*)(Bb + ((size_t)(cb + lane) << 3)),
                                             (luint*)&lB[(size_t)cb << 3], 16, 0, 0);
        }
        __syncthreads();

        #pragma unroll
        for (int ks = 0; ks < 2; ++ks) {
            bf16x8 af[4], bfv[4];
            #pragma unroll
            for (int mi = 0; mi < 4; ++mi)
                af[mi] = *(const bf16x8*)&lA[((((wr * 4 + mi) << 1) | ks) << 9) + lane * 8];
            #pragma unroll
            for (int ni = 0; ni < 4; ++ni)
                bfv[ni] = *(const bf16x8*)&lB[((((wc * 4 + ni) << 1) | ks) << 9) + lane * 8];
            #pragma unroll
            for (int mi = 0; mi < 4; ++mi)
                #pragma unroll
                for (int ni = 0; ni < 4; ++ni)
                    acc[mi][ni] = __builtin_amdgcn_mfma_f32_16x16x32_bf16(af[mi], bfv[ni], acc[mi][ni], 0, 0, 0);
        }
        __syncthreads();
    }

    // ---- epilogue: logits = acc*10; exp; row-sums -> LDS reduce; store positives ----
    float* redf = (float*)lA;               // 2 * 128 floats, safe after final barrier
    const int cj = (ct >> 4) + 1;           // class of this col tile (1..18)
    const int colbase = ct * BN + wc * 64 + (lane & 15);
    const int g = lane >> 4;
    #pragma unroll
    for (int mi = 0; mi < 4; ++mi) {
        #pragma unroll
        for (int rj = 0; rj < 4; ++rj) {
            const int rloc = wr * 64 + mi * 16 + g * 4 + rj;
            const int r = rt * BM + rloc;
            const bool isPos = (y[r & 255] == cj);
            float rs = 0.0f;
            #pragma unroll
            for (int ni = 0; ni < 4; ++ni) {
                const float lv = acc[mi][ni][rj] * INV_TEMP;
                rs += __expf(lv);
                if (isPos) pos[(size_t)r * BANK + ((colbase + ni * 16) & (BANK - 1))] = lv;
            }
            rs += __shfl_xor(rs, 1);
            rs += __shfl_xor(rs, 2);
            rs += __shfl_xor(rs, 4);
            rs += __shfl_xor(rs, 8);
            if ((lane & 15) == 0) redf[wc * 128 + rloc] = rs;
        }
    }
    __syncthreads();
    if (t < BM) part[(size_t)ct * NROWS + rt * BM + t] = redf[t] + redf[128 + t];
}

// Pass 3: per-row finish. S_all = sum_ct part[ct][r]; N = S_all - posExpSum + 2048.
// P = sum over positives of (l - log(exp(l)+N)), excluding diagonal for class-1 rows.
__global__ __launch_bounds__(256) void pass3_kernel(
    const int* __restrict__ y, const float* __restrict__ part,
    const float* __restrict__ pos, float* __restrict__ out)
{
    __shared__ float sh[12];
    const int r = blockIdx.x;
    const int t = threadIdx.x;
    const int c = y[r & 255];
    const float4_t* row4 = (const float4_t*)(pos + (size_t)r * BANK);
    float4_t va = row4[t];
    float4_t vb = row4[t + 256];
    float l[8] = { va.x, va.y, va.z, va.w, vb.x, vb.y, vb.z, vb.w };
    float e[8];
    float eSum = 0.0f;
    #pragma unroll
    for (int i = 0; i < 8; ++i) { e[i] = __expf(l[i]); eSum += e[i]; }
    float sa = 0.0f;
    for (int ctb = t; ctb < NCT; ctb += 256) sa += part[(size_t)ctb * NROWS + r];
    #pragma unroll
    for (int m = 1; m < 64; m <<= 1) {
        eSum += __shfl_xor(eSum, m);
        sa   += __shfl_xor(sa, m);
    }
    const int w = t >> 6;
    if ((t & 63) == 0) { sh[w] = eSum; sh[4 + w] = sa; }
    __syncthreads();
    const float eTot  = sh[0] + sh[1] + sh[2] + sh[3];
    const float saTot = sh[4] + sh[5] + sh[6] + sh[7];
    const float N = saTot - eTot + (float)BANK;

    float P = 0.0f;
    #pragma unroll
    for (int i = 0; i < 8; ++i) {
        const int m = (i < 4) ? (4 * t + i) : (1024 + 4 * t + (i - 4));
        const bool skip = (c == 1) && (m == r);
        if (!skip) P += l[i] - __logf(e[i] + N);
    }
    #pragma unroll
    for (int m = 1; m < 64; m <<= 1) P += __shfl_xor(P, m);
    if ((t & 63) == 0) sh[8 + w] = P;
    __syncthreads();
    if (t == 0) {
        const float Ptot = sh[8] + sh[9] + sh[10] + sh[11];
        const float denom = (c == 1) ? (float)(BANK - 1) : (float)BANK;
        atomicAdd(out, (-Ptot / denom) * (1.0f / (float)NROWS));
    }
}

extern "C" void kernel_launch(void* const* d_in, const int* in_sizes, int n_in,
                              void* d_out, int out_size, void* d_ws, size_t ws_size,
                              hipStream_t stream) {
    const float* X = (const float*)d_in[0];
    const int*   y = (const int*)d_in[1];
    const float* Q = (const float*)d_in[2];
    float* out  = (float*)d_out;
    float* pos  = (float*)d_ws;                                  // 2048*2048 f32 (16.8 MB)
    float* part = pos + (size_t)NROWS * BANK;                    // 288*2048 f32 (2.36 MB)
    unsigned short* Abuf = (unsigned short*)(part + (size_t)NCT * NROWS);   // 1 MB
    unsigned short* Bbuf = Abuf + ((size_t)A_CHUNKS << 3);                  // 18.9 MB

    zero_kernel<<<dim3(1), dim3(256), 0, stream>>>(out);
    pass0_pack<<<dim3(TOT_CHUNKS / 256), dim3(256), 0, stream>>>(X, Q, Abuf, Bbuf);
    pass1_gemm<<<dim3(16, 288), dim3(256), 0, stream>>>(Abuf, Bbuf, y, part, pos);
    pass3_kernel<<<dim3(NROWS), dim3(256), 0, stream>>>(y, part, pos, out);
}